// Round 2
// baseline (544.960 us; speedup 1.0000x reference)
//
#include <hip/hip_runtime.h>
#include <math.h>

#define BB 32
#define MM 2048
#define NN 512
#define PSZ 16
#define HH 640
#define WW 640
#define DD 256
#define DIMG_ 384
#define NHEADS 8
#define PD_ 768
#define TWO_N 1024
#define ROWS_TOT (BB * TWO_N)          // 32768 patch rows
#define CHCT 32                        // ctx key-chunks per batch (32 keys each)

typedef short bf16x8 __attribute__((ext_vector_type(8)));
typedef float f32x4  __attribute__((ext_vector_type(4)));

// ---- fp32 -> bf16 (RNE) helpers -------------------------------------------
__device__ __forceinline__ unsigned short f2bf(float x) {
  unsigned int u = __float_as_uint(x);
  u = (u + 0x7FFF + ((u >> 16) & 1)) >> 16;
  return (unsigned short)u;
}
__device__ __forceinline__ float bf2f(unsigned short h) {
  return __uint_as_float(((unsigned int)h) << 16);
}

// ---- async global->LDS (16B per lane, lds base must be wave-uniform) ------
__device__ __forceinline__ void gload_lds16(const void* g, void* l) {
  __builtin_amdgcn_global_load_lds(
      (const __attribute__((address_space(1))) void*)g,
      (__attribute__((address_space(3))) void*)l, 16, 0, 0);
}

// ---------------------------------------------------------------------------
// Kernel 1 (fused prep + extract):
//   blocks [0,768)   : W_pe -> Whi/Wlo bf16 split
//   blocks [768,800) : per-batch q projections + logits-side precompute:
//       u[h][:] (kept in LDS), v_h = W_pe^T (g .* u_h) -> Vhi/Vlo bf16 split,
//       Pc[b] = {S1,S2,S3,u255,ubias}[8]
//   blocks [800,...) : patch extract + LN1 -> Ahi/Alo + score
// ---------------------------------------------------------------------------
__global__ __launch_bounds__(256) void prep_extract_kernel(
    const float* __restrict__ W_pe,
    unsigned short* __restrict__ Whi, unsigned short* __restrict__ Wlo,
    const float* __restrict__ image_embs,
    const float* __restrict__ W_proj, const float* __restrict__ b_proj,
    const float* __restrict__ in_w,   const float* __restrict__ in_b,
    const float* __restrict__ b_pe,
    const float* __restrict__ ln2_g, const float* __restrict__ ln2_b,
    unsigned short* __restrict__ Vhi, unsigned short* __restrict__ Vlo,
    float* __restrict__ Pc,
    const float* __restrict__ im0, const float* __restrict__ im1,
    const float* __restrict__ kpts0, const float* __restrict__ kpts1,
    const float* __restrict__ scores0, const float* __restrict__ scores1,
    const int*   __restrict__ sorted_matches,
    const float* __restrict__ ln1_g, const float* __restrict__ ln1_b,
    unsigned short* __restrict__ Ahi, unsigned short* __restrict__ Alo,
    float* __restrict__ score_all)
{
  __shared__ float q1[DD];
  __shared__ float q2s[DD];
  __shared__ float u_sh[NHEADS][DD];     // 8 KB
  __shared__ float gu_sh[DD][NHEADS];    // 8 KB, [c][h] for float4 reads
  __shared__ float sred[NHEADS][3][4];
  const int t = threadIdx.x;

  if (blockIdx.x < 768) {                 // ---- W conversion ----
    const int idx = blockIdx.x * 256 + t;
    const int row = idx / PD_;
    float v = (row < 255) ? W_pe[idx] : 0.0f;
    const unsigned short h = f2bf(v);
    Whi[idx] = h;
    Wlo[idx] = f2bf(v - bf2f(h));
    return;
  }

  if (blockIdx.x < 800) {                 // ---- per-batch q-side precompute ----
    const int b = blockIdx.x - 768;
    {
      const float4* emb = (const float4*)(image_embs + (size_t)b * DIMG_);
      const float4* wr  = (const float4*)(W_proj + (size_t)t * DIMG_);
      float a = b_proj[t];
      #pragma unroll 4
      for (int i = 0; i < DIMG_ / 4; ++i) {
        const float4 e4 = emb[i], w4 = wr[i];
        a += e4.x * w4.x + e4.y * w4.y + e4.z * w4.z + e4.w * w4.w;
      }
      q1[t] = a;
    }
    __syncthreads();
    {
      const float4* wr = (const float4*)(in_w + (size_t)t * DD);
      const float4* qq = (const float4*)q1;
      float a = in_b[t];
      #pragma unroll 4
      for (int i = 0; i < DD / 4; ++i) {
        const float4 q4 = qq[i], w4 = wr[i];
        a += q4.x * w4.x + q4.y * w4.y + q4.z * w4.z + q4.w * w4.w;
      }
      q2s[t] = a;
    }
    __syncthreads();
    #pragma unroll
    for (int h = 0; h < NHEADS; ++h) {
      float s = 0.0f;
      #pragma unroll 8
      for (int i = 0; i < 32; ++i)
        s += q2s[h * 32 + i] * in_w[(size_t)(DD + h * 32 + i) * DD + t];
      u_sh[h][t] = s;
    }
    float ubv = 0.0f;
    if (t < NHEADS) {
      for (int i = 0; i < 32; ++i) ubv += q2s[t * 32 + i] * in_b[DD + t * 32 + i];
    }
    __syncthreads();

    // gu + S1/S2/S3 partials (thread t == channel c)
    const bool cvld = (t < 255);
    const float g_c = cvld ? ln2_g[t] : 0.0f;
    const float bb_c = cvld ? ln2_b[t] : 0.0f;
    const float pp_c = cvld ? b_pe[t]  : 0.0f;
    const int wv = t >> 6, ln = t & 63;
    #pragma unroll
    for (int h = 0; h < NHEADS; ++h) {
      const float u_c = u_sh[h][t];
      const float gu  = g_c * u_c;
      gu_sh[t][h] = gu;
      float x1 = gu, x2 = bb_c * u_c, x3 = pp_c * gu;
      #pragma unroll
      for (int m = 32; m; m >>= 1) {
        x1 += __shfl_xor(x1, m); x2 += __shfl_xor(x2, m); x3 += __shfl_xor(x3, m);
      }
      if (ln == 0) { sred[h][0][wv] = x1; sred[h][1][wv] = x2; sred[h][2][wv] = x3; }
    }
    __syncthreads();
    if (t < NHEADS) {
      const float S1 = sred[t][0][0] + sred[t][0][1] + sred[t][0][2] + sred[t][0][3];
      const float S2 = sred[t][1][0] + sred[t][1][1] + sred[t][1][2] + sred[t][1][3];
      const float S3 = sred[t][2][0] + sred[t][2][1] + sred[t][2][2] + sred[t][2][3];
      float* pc = Pc + b * 40;
      pc[t]      = S1;
      pc[8 + t]  = S2;
      pc[16 + t] = S3;
      pc[24 + t] = u_sh[t][255];
      pc[32 + t] = ubv;
    }

    // v_h[k] = sum_{c<255} W_pe[c][k] * gu[c][h]  -> split bf16 rows of B-ext
    #pragma unroll
    for (int kk = 0; kk < 3; ++kk) {
      const int k = t + 256 * kk;
      float vh[NHEADS] = {0, 0, 0, 0, 0, 0, 0, 0};
      for (int c = 0; c < 255; ++c) {
        const float wv_ = W_pe[(size_t)c * PD_ + k];
        const float4 g0 = *(const float4*)&gu_sh[c][0];
        const float4 g1 = *(const float4*)&gu_sh[c][4];
        vh[0] += wv_ * g0.x; vh[1] += wv_ * g0.y; vh[2] += wv_ * g0.z; vh[3] += wv_ * g0.w;
        vh[4] += wv_ * g1.x; vh[5] += wv_ * g1.y; vh[6] += wv_ * g1.z; vh[7] += wv_ * g1.w;
      }
      #pragma unroll
      for (int h = 0; h < NHEADS; ++h) {
        const unsigned short hi = f2bf(vh[h]);
        Vhi[((size_t)b * 16 + h) * PD_ + k] = hi;
        Vlo[((size_t)b * 16 + h) * PD_ + k] = f2bf(vh[h] - bf2f(hi));
      }
      #pragma unroll
      for (int h = NHEADS; h < 16; ++h) {       // zero pad rows 8..15
        Vhi[((size_t)b * 16 + h) * PD_ + k] = 0;
        Vlo[((size_t)b * 16 + h) * PD_ + k] = 0;
      }
    }
    return;
  }

  // ---- patch extract + LN1 (one wave per patch) ----
  const int L  = t & 63;
  const long gp = (long)(blockIdx.x - 800) * 4 + (t >> 6);
  const int b   = (int)(gp >> 10);
  const int n2  = (int)(gp & 1023);
  const bool side1 = (n2 >= NN);
  const float* img  = side1 ? im1 : im0;
  const float* kpts = side1 ? kpts1 : kpts0;
  const float* scrs = side1 ? scores1 : scores0;

  const int n  = side1 ? (n2 - NN) : n2;
  const int m0 = sorted_matches[((size_t)b * NN + n) * 2 + 0];
  const int m1 = sorted_matches[((size_t)b * NN + n) * 2 + 1];
  const bool valid = (m1 > -1);
  int midx = side1 ? m1 : m0;
  midx = min(max(midx, 0), MM - 1);
  const float kx = kpts[((size_t)b * MM + midx) * 2 + 0];
  const float ky = kpts[((size_t)b * MM + midx) * 2 + 1];
  const int x0 = min(max((int)rintf(kx) - 8, 0), WW - PSZ);
  const int y0 = min(max((int)rintf(ky) - 8, 0), HH - PSZ);

  float v[12];
  if (valid) {
    const size_t imb = (size_t)b * 3 * HH * WW;
    const int px = (2 * L) & 15;
    #pragma unroll
    for (int j = 0; j < 6; ++j) {
      const int p0 = 2 * L + 128 * j;
      const int c  = p0 >> 8;
      const int py = (p0 >> 4) & 15;
      const float* rp = img + imb + ((size_t)c * HH + y0 + py) * WW + x0 + px;
      v[2 * j]     = fminf(fmaxf(rp[0], 0.0f), 1.0f);
      v[2 * j + 1] = fminf(fmaxf(rp[1], 0.0f), 1.0f);
    }
  } else {
    #pragma unroll
    for (int i = 0; i < 12; ++i) v[i] = -1.0f;
  }

  float s = 0.0f, ss = 0.0f;
  #pragma unroll
  for (int i = 0; i < 12; ++i) { s += v[i]; ss += v[i] * v[i]; }
  #pragma unroll
  for (int m = 32; m; m >>= 1) { s += __shfl_xor(s, m); ss += __shfl_xor(ss, m); }
  const float mu  = s * (1.0f / 768.0f);
  const float var = ss * (1.0f / 768.0f) - mu * mu;
  const float rs  = 1.0f / sqrtf(var + 1e-5f);

  unsigned int* AhiW = (unsigned int*)(Ahi + gp * PD_);
  unsigned int* AloW = (unsigned int*)(Alo + gp * PD_);
  #pragma unroll
  for (int j = 0; j < 6; ++j) {
    const int p0 = 2 * L + 128 * j;
    const float y0e = (v[2 * j]     - mu) * rs * ln1_g[p0]     + ln1_b[p0];
    const float y1e = (v[2 * j + 1] - mu) * rs * ln1_g[p0 + 1] + ln1_b[p0 + 1];
    const unsigned short h0 = f2bf(y0e), h1 = f2bf(y1e);
    AhiW[p0 >> 1] = (unsigned int)h0 | ((unsigned int)h1 << 16);
    const unsigned short l0 = f2bf(y0e - bf2f(h0));
    const unsigned short l1 = f2bf(y1e - bf2f(h1));
    AloW[p0 >> 1] = (unsigned int)l0 | ((unsigned int)l1 << 16);
  }
  if (L == 0) {
    score_all[gp] = valid ? scrs[(size_t)b * MM + midx] : 0.0f;
  }
}

// ---------------------------------------------------------------------------
// Kernel 2: fused GEMM + LN2 + logits.
// Tile: 64 rows x 272 cols (256 e-cols + 16 v-cols for logits), BK=32,
// 4 waves (256 thr), 43 KB LDS, 512 blocks = 2 independent blocks/CU.
// m97 2-barrier single-buffer schedule (cross-block overlap hides drain).
// Wave w covers cols [w*64, w*64+64); wave 3 additionally cols 256..271
// (the per-batch v rows -> logits T = A.v_h via MFMA, no epilogue transpose).
// Epilogue: LN2 stats via 2.5 KB LDS reduce (aliased onto staging), write pe,
// lt[row][h] = (rs*(T + S3 - mu*S1) + S2 + score*u255 + ubias) * scale.
// ---------------------------------------------------------------------------
__global__ __launch_bounds__(256, 2) void gemm_fused_kernel(
    const unsigned short* __restrict__ Ahi, const unsigned short* __restrict__ Alo,
    const unsigned short* __restrict__ Whi, const unsigned short* __restrict__ Wlo,
    const unsigned short* __restrict__ Vhi, const unsigned short* __restrict__ Vlo,
    const float* __restrict__ b_pe,
    const float* __restrict__ ln2_g, const float* __restrict__ ln2_b,
    const float* __restrict__ score_all,
    const float* __restrict__ Pc,
    float* __restrict__ pe, float* __restrict__ lt)
{
  // shorts: AHI [64][32] @0, ALO @2048, BHI [272][32] @4096, BLO @12800
  __shared__ __align__(16) unsigned short sm[21504];   // 43008 B
  const int t = threadIdx.x;
  const int w = t >> 6, L = t & 63;
  const int mt = blockIdx.x;                 // 512 blocks, 64 rows each
  const int bidx = mt >> 4;                  // 16 blocks per batch

  const int rr   = L >> 2;                   // row within 16-row chunk
  const int q_st = (L & 3) ^ ((L >> 4) & 3); // XOR-swizzled k-quad (store)
  const int lane_m = L & 15, quad = L >> 4;
  const int swz = quad ^ (lane_m >> 2);      // same swizzle on read

  // ---- staging chunk map: 42 x 1KB chunks; wave w owns cc = w + 4c ----
  const unsigned short* gsrc[11];
  int ldst[11];
  #pragma unroll
  for (int c = 0; c < 11; ++c) {
    const int cc = w + 4 * c;
    const unsigned short* sp = Ahi; long rb = 0; int dst = 0;
    if (cc < 4)       { sp = Ahi; rb = (long)mt * 64 + cc * 16;       dst = cc * 512; }
    else if (cc < 8)  { sp = Alo; rb = (long)mt * 64 + (cc - 4) * 16; dst = 2048 + (cc - 4) * 512; }
    else if (cc < 25) { const int r0 = (cc - 8) * 16;
                        sp = (r0 < 256) ? (Whi + (long)r0 * PD_)
                                        : (Vhi + (long)bidx * 16 * PD_);
                        dst = 4096 + (cc - 8) * 512; }
    else if (cc < 42) { const int r0 = (cc - 25) * 16;
                        sp = (r0 < 256) ? (Wlo + (long)r0 * PD_)
                                        : (Vlo + (long)bidx * 16 * PD_);
                        dst = 12800 + (cc - 25) * 512; }
    gsrc[c] = sp + (rb + rr) * (long)PD_ + q_st * 8;
    ldst[c] = dst;
  }
  const int CNT = (w < 2) ? 11 : 10;
  const int JW  = (w == 3) ? 5 : 4;

  f32x4 acc[4][5];
  #pragma unroll
  for (int i = 0; i < 4; ++i)
    #pragma unroll
    for (int j = 0; j < 5; ++j) acc[i][j] = (f32x4){0.f, 0.f, 0.f, 0.f};

  for (int ks = 0; ks < PD_ / 32; ++ks) {
    const int k0 = ks * 32;
    __syncthreads();                          // LDS free to overwrite
    #pragma unroll
    for (int c = 0; c < 11; ++c)
      if (c < CNT) gload_lds16(gsrc[c] + k0, sm + ldst[c]);
    __syncthreads();                          // staging complete (vmcnt drain)

    bf16x8 ah[4], al[4];
    #pragma unroll
    for (int i = 0; i < 4; ++i) {
      const int offa = (i * 16 + lane_m) * 32 + swz * 8;
      ah[i] = *(const bf16x8*)(sm + offa);
      al[i] = *(const bf16x8*)(sm + 2048 + offa);
    }
    #pragma unroll
    for (int j = 0; j < 5; ++j) {
      if (j < JW) {
        const int offb = (w * 64 + j * 16 + lane_m) * 32 + swz * 8;
        const bf16x8 bh = *(const bf16x8*)(sm + 4096 + offb);
        const bf16x8 bl = *(const bf16x8*)(sm + 12800 + offb);
        #pragma unroll
        for (int i = 0; i < 4; ++i) {
          acc[i][j] = __builtin_amdgcn_mfma_f32_16x16x32_bf16(ah[i], bh, acc[i][j], 0, 0, 0);
          acc[i][j] = __builtin_amdgcn_mfma_f32_16x16x32_bf16(ah[i], bl, acc[i][j], 0, 0, 0);
          acc[i][j] = __builtin_amdgcn_mfma_f32_16x16x32_bf16(al[i], bh, acc[i][j], 0, 0, 0);
        }
      }
    }
  }

  // ---- fused epilogue ----
  __syncthreads();                            // staging reads done; alias LDS
  float* const fs = (float*)sm;               // [0,256) s  [256,512) ss
                                              // [512,576) mu [576,640) rs
  // per-lane channel constants for my 4 main col-blocks
  float p4[4], g4[4], b4[4];
  #pragma unroll
  for (int j = 0; j < 4; ++j) {
    const int c = w * 64 + j * 16 + lane_m;
    const bool cv = (c < 255);
    p4[j] = cv ? b_pe[c]  : 0.0f;
    g4[j] = cv ? ln2_g[c] : 0.0f;
    b4[j] = cv ? ln2_b[c] : 0.0f;
  }
  // stats: col 255 contributes exactly 0 (e==0 from zero W row, p4==0)
  float sv[16], qv[16];
  #pragma unroll
  for (int i = 0; i < 4; ++i)
    #pragma unroll
    for (int v = 0; v < 4; ++v) {
      float s = 0.0f, q = 0.0f;
      #pragma unroll
      for (int j = 0; j < 4; ++j) {
        const float x = acc[i][j][v] + p4[j];
        s += x; q += x * x;
      }
      sv[i * 4 + v] = s; qv[i * 4 + v] = q;
    }
  #pragma unroll
  for (int iv = 0; iv < 16; ++iv) {
    #pragma unroll
    for (int m = 1; m <= 8; m <<= 1) {
      sv[iv] += __shfl_xor(sv[iv], m);
      qv[iv] += __shfl_xor(qv[iv], m);
    }
  }
  if (lane_m == 0) {
    #pragma unroll
    for (int i = 0; i < 4; ++i)
      #pragma unroll
      for (int v = 0; v < 4; ++v) {
        const int row = i * 16 + quad * 4 + v;
        fs[w * 64 + row]       = sv[i * 4 + v];
        fs[256 + w * 64 + row] = qv[i * 4 + v];
      }
  }
  __syncthreads();
  if (t < 64) {
    const float S  = fs[t] + fs[64 + t] + fs[128 + t] + fs[192 + t];
    const float SS = fs[256 + t] + fs[320 + t] + fs[384 + t] + fs[448 + t];
    const float mu  = S * (1.0f / 255.0f);
    const float var = SS * (1.0f / 255.0f) - mu * mu;
    fs[512 + t] = mu;
    fs[576 + t] = 1.0f / sqrtf(var + 1e-5f);
  }
  __syncthreads();

  // per-batch logit constants (wave 3 only uses them)
  float S1 = 0, S2 = 0, S3 = 0, u255 = 0, ubias = 0;
  if (w == 3 && lane_m < NHEADS) {
    const float* pc = Pc + bidx * 40;
    S1 = pc[lane_m]; S2 = pc[8 + lane_m]; S3 = pc[16 + lane_m];
    u255 = pc[24 + lane_m]; ubias = pc[32 + lane_m];
  }

  #pragma unroll
  for (int i = 0; i < 4; ++i)
    #pragma unroll
    for (int v = 0; v < 4; ++v) {
      const int row = i * 16 + quad * 4 + v;
      const long grow = (long)mt * 64 + row;
      const float mu = fs[512 + row];
      const float rs = fs[576 + row];
      float sc = 0.0f;
      if (w == 3) sc = score_all[grow];              // broadcast within quad-group
      float* rowp = pe + grow * DD + w * 64 + lane_m;
      #pragma unroll
      for (int j = 0; j < 4; ++j) {
        const int c = w * 64 + j * 16 + lane_m;
        const float y = (c < 255)
            ? (acc[i][j][v] + p4[j] - mu) * rs * g4[j] + b4[j]
            : sc;
        rowp[j * 16] = y;
      }
      if (w == 3 && lane_m < NHEADS) {
        const float T = acc[i][4][v];
        const float d = rs * (T + S3 - mu * S1) + S2 + sc * u255;
        lt[grow * NHEADS + lane_m] = (d + ubias) * 0.17677669529663687f; // 1/sqrt(32)
      }
    }
}

// ---------------------------------------------------------------------------
// Kernel 3: softmax over 1024 keys per batch -> prg[b][k][h] (1 MB, L2)
// ---------------------------------------------------------------------------
__global__ __launch_bounds__(256) void softmax_kernel(
    const float* __restrict__ lt, float* __restrict__ prg)
{
  const int b = blockIdx.x, t = threadIdx.x;
  const int h = t >> 5, l = t & 31;
  const float* base = lt + (size_t)b * TWO_N * NHEADS + h;
  float v[32];
  float mx = -1e30f;
  #pragma unroll 8
  for (int i = 0; i < 32; ++i) { v[i] = base[(l + 32 * i) * NHEADS]; mx = fmaxf(mx, v[i]); }
  #pragma unroll
  for (int m = 16; m; m >>= 1) mx = fmaxf(mx, __shfl_xor(mx, m, 32));
  float sm = 0.0f;
  #pragma unroll 8
  for (int i = 0; i < 32; ++i) { v[i] = expf(v[i] - mx); sm += v[i]; }
  #pragma unroll
  for (int m = 16; m; m >>= 1) sm += __shfl_xor(sm, m, 32);
  const float inv = 1.0f / sm;
  float* out = prg + (size_t)b * TWO_N * NHEADS + h;
  #pragma unroll 8
  for (int i = 0; i < 32; ++i) out[(l + 32 * i) * NHEADS] = v[i] * inv;
}

// ---------------------------------------------------------------------------
// Kernel 4: partial ctx over 32-key chunks. 1024 blocks (4/CU), 1 KB LDS.
// ---------------------------------------------------------------------------
__global__ __launch_bounds__(256) void ctx_kernel(
    const float* __restrict__ pe, const float* __restrict__ prg,
    float* __restrict__ ctxp)
{
  __shared__ __align__(16) float prc[32 * NHEADS];   // 1 KB
  const int b = blockIdx.x, ch = blockIdx.y, t = threadIdx.x;
  prc[t] = prg[((size_t)b * TWO_N + ch * 32) * NHEADS + t];
  __syncthreads();

  const float* peb = pe + ((size_t)b * TWO_N + ch * 32) * DD;
  float acc[NHEADS] = {0, 0, 0, 0, 0, 0, 0, 0};
  #pragma unroll 4
  for (int k = 0; k < 32; ++k) {
    const float v = peb[(size_t)k * DD + t];           // coalesced
    const float4 a0 = *(const float4*)&prc[k * NHEADS];
    const float4 a1 = *(const float4*)&prc[k * NHEADS + 4];
    acc[0] += a0.x * v; acc[1] += a0.y * v; acc[2] += a0.z * v; acc[3] += a0.w * v;
    acc[4] += a1.x * v; acc[5] += a1.y * v; acc[6] += a1.z * v; acc[7] += a1.w * v;
  }
  #pragma unroll
  for (int h = 0; h < NHEADS; ++h)
    ctxp[(((size_t)b * CHCT + ch) * NHEADS + h) * DD + t] = acc[h];
}

// ---------------------------------------------------------------------------
// Kernel 5: reduce ctx partials + Wv + out_w + W_fc head
// ---------------------------------------------------------------------------
__global__ __launch_bounds__(256) void final_kernel(
    const float* __restrict__ ctxp,
    const float* __restrict__ in_w,  const float* __restrict__ in_b,
    const float* __restrict__ out_w, const float* __restrict__ out_b,
    const float* __restrict__ W_fc,  const float* __restrict__ b_fc,
    float* __restrict__ outp)
{
  __shared__ __align__(16) float ctx_sh[NHEADS * DD];
  __shared__ __align__(16) float o_sh[DD], o2_sh[DD];
  const int t = threadIdx.x;
  const int b = blockIdx.x;

  #pragma unroll
  for (int h = 0; h < NHEADS; ++h) {
    float s = 0.0f;
    #pragma unroll
    for (int ch = 0; ch < CHCT; ++ch)
      s += ctxp[(((size_t)b * CHCT + ch) * NHEADS + h) * DD + t];
    ctx_sh[h * DD + t] = s;
  }
  __syncthreads();
  {
    const float4* wv = (const float4*)(in_w + (size_t)(2 * DD + t) * DD);
    const float4* cx = (const float4*)(ctx_sh + (t >> 5) * DD);
    float o1 = in_b[2 * DD + t];
    #pragma unroll 4
    for (int j = 0; j < DD / 4; ++j) {
      const float4 w4 = wv[j], c4 = cx[j];
      o1 += w4.x * c4.x + w4.y * c4.y + w4.z * c4.z + w4.w * c4.w;
    }
    o_sh[t] = o1;
  }
  __syncthreads();
  {
    const float4* wr = (const float4*)(out_w + (size_t)t * DD);
    const float4* oo = (const float4*)o_sh;
    float o2 = out_b[t];
    #pragma unroll 4
    for (int j = 0; j < DD / 4; ++j) {
      const float4 w4 = wr[j], c4 = oo[j];
      o2 += w4.x * c4.x + w4.y * c4.y + w4.z * c4.z + w4.w * c4.w;
    }
    o2_sh[t] = o2;
  }
  __syncthreads();
  if (t < 6) {
    const float4* wr = (const float4*)(W_fc + (size_t)t * DD);
    const float4* oo = (const float4*)o2_sh;
    float r = b_fc[t];
    for (int j = 0; j < DD / 4; ++j) {
      const float4 w4 = wr[j], c4 = oo[j];
      r += w4.x * c4.x + w4.y * c4.y + w4.z * c4.z + w4.w * c4.w;
    }
    outp[b * 6 + t] = r;
  }
}

// ---------------------------------------------------------------------------
extern "C" void kernel_launch(void* const* d_in, const int* in_sizes, int n_in,
                              void* d_out, int out_size, void* d_ws, size_t ws_size,
                              hipStream_t stream) {
  const float* im0       = (const float*)d_in[0];
  const float* im1       = (const float*)d_in[1];
  const float* kpts0     = (const float*)d_in[2];
  const float* kpts1     = (const float*)d_in[3];
  const float* scores0   = (const float*)d_in[4];
  const float* scores1   = (const float*)d_in[5];
  const float* image_embs= (const float*)d_in[6];
  const int*   smatch    = (const int*)d_in[7];
  const float* ln1_g     = (const float*)d_in[8];
  const float* ln1_b     = (const float*)d_in[9];
  const float* W_pe      = (const float*)d_in[10];
  const float* b_pe      = (const float*)d_in[11];
  const float* ln2_g     = (const float*)d_in[12];
  const float* ln2_b     = (const float*)d_in[13];
  const float* W_proj    = (const float*)d_in[14];
  const float* b_proj    = (const float*)d_in[15];
  const float* in_w      = (const float*)d_in[16];
  const float* in_b      = (const float*)d_in[17];
  const float* out_w     = (const float*)d_in[18];
  const float* out_b     = (const float*)d_in[19];
  const float* W_fc      = (const float*)d_in[20];
  const float* b_fc      = (const float*)d_in[21];

  // ---- workspace layout (bytes) ----
  char* ws = (char*)d_ws;
  size_t off = 0;
  float* epe   = (float*)(ws + off); off += (size_t)ROWS_TOT * DD * 4;        // 32 MB (pe)
  float* score = (float*)(ws + off); off += (size_t)ROWS_TOT * 4;             // 128 KB
  float* lt    = (float*)(ws + off); off += (size_t)BB * TWO_N * NHEADS * 4;  // 1 MB
  float* prg   = (float*)(ws + off); off += (size_t)BB * TWO_N * NHEADS * 4;  // 1 MB
  float* ctxp  = (float*)(ws + off); off += (size_t)BB * CHCT * NHEADS * DD * 4; // 8 MB
  float* Pc    = (float*)(ws + off); off += (size_t)BB * 40 * 4;
  off = (off + 1023) & ~(size_t)1023;
  unsigned short* Whi = (unsigned short*)(ws + off); off += (size_t)256 * PD_ * 2;
  unsigned short* Wlo = (unsigned short*)(ws + off); off += (size_t)256 * PD_ * 2;
  unsigned short* Vhi = (unsigned short*)(ws + off); off += (size_t)BB * 16 * PD_ * 2;
  unsigned short* Vlo = (unsigned short*)(ws + off); off += (size_t)BB * 16 * PD_ * 2;
  off = (off + 1023) & ~(size_t)1023;
  unsigned short* Ahi = (unsigned short*)(ws + off); off += (size_t)ROWS_TOT * PD_ * 2; // 50 MB
  unsigned short* Alo = (unsigned short*)(ws + off); off += (size_t)ROWS_TOT * PD_ * 2; // 50 MB

  prep_extract_kernel<<<800 + ROWS_TOT / 4, 256, 0, stream>>>(
      W_pe, Whi, Wlo, image_embs, W_proj, b_proj, in_w, in_b,
      b_pe, ln2_g, ln2_b, Vhi, Vlo, Pc,
      im0, im1, kpts0, kpts1, scores0, scores1, smatch,
      ln1_g, ln1_b, Ahi, Alo, score);
  gemm_fused_kernel<<<ROWS_TOT / 64, 256, 0, stream>>>(
      Ahi, Alo, Whi, Wlo, Vhi, Vlo, b_pe, ln2_g, ln2_b, score, Pc, epe, lt);
  softmax_kernel<<<BB, 256, 0, stream>>>(lt, prg);
  ctx_kernel<<<dim3(BB, CHCT), 256, 0, stream>>>(epe, prg, ctxp);
  final_kernel<<<BB, 256, 0, stream>>>(ctxp, in_w, in_b, out_w, out_b,
                                       W_fc, b_fc, (float*)d_out);
}

// Round 3
// 473.112 us; speedup vs baseline: 1.1519x; 1.1519x over previous
//
#include <hip/hip_runtime.h>
#include <math.h>

#define BB 32
#define MM 2048
#define NN 512
#define PSZ 16
#define HH 640
#define WW 640
#define DD 256
#define DIMG_ 384
#define NHEADS 8
#define PD_ 768
#define TWO_N 1024
#define ROWS_TOT (BB * TWO_N)          // 32768 patch rows
#define CHCT 32                        // ctx key-chunks per batch (32 keys each)

typedef short bf16x8 __attribute__((ext_vector_type(8)));
typedef float f32x4  __attribute__((ext_vector_type(4)));

// ---- fp32 -> bf16 (RNE) helpers -------------------------------------------
__device__ __forceinline__ unsigned short f2bf(float x) {
  unsigned int u = __float_as_uint(x);
  u = (u + 0x7FFF + ((u >> 16) & 1)) >> 16;
  return (unsigned short)u;
}
__device__ __forceinline__ float bf2f(unsigned short h) {
  return __uint_as_float(((unsigned int)h) << 16);
}

// ---- async global->LDS (16B per lane, lds base must be wave-uniform) ------
__device__ __forceinline__ void gload_lds16(const void* g, void* l) {
  __builtin_amdgcn_global_load_lds(
      (const __attribute__((address_space(1))) void*)g,
      (__attribute__((address_space(3))) void*)l, 16, 0, 0);
}

// ---------------------------------------------------------------------------
// Kernel 1 (fused prep + extract):
//   blocks [0,768)   : W_pe -> Whi/Wlo bf16 split
//   blocks [768,800) : q projections (u[b,h,:] over all 256 cols, ubias[b,h])
//   blocks [800,...) : patch extract + LN1 -> Ahi/Alo + score
// (v_h precompute removed: it made the 32 q-blocks a 186 us serial tail.)
// ---------------------------------------------------------------------------
__global__ __launch_bounds__(256) void prep_extract_kernel(
    const float* __restrict__ W_pe,
    unsigned short* __restrict__ Whi, unsigned short* __restrict__ Wlo,
    const float* __restrict__ image_embs,
    const float* __restrict__ W_proj, const float* __restrict__ b_proj,
    const float* __restrict__ in_w,   const float* __restrict__ in_b,
    float* __restrict__ u_out, float* __restrict__ bias_out,
    const float* __restrict__ im0, const float* __restrict__ im1,
    const float* __restrict__ kpts0, const float* __restrict__ kpts1,
    const float* __restrict__ scores0, const float* __restrict__ scores1,
    const int*   __restrict__ sorted_matches,
    const float* __restrict__ ln1_g, const float* __restrict__ ln1_b,
    unsigned short* __restrict__ Ahi, unsigned short* __restrict__ Alo,
    float* __restrict__ score_all)
{
  __shared__ float q1[DD];
  __shared__ float q2[DD];
  const int t = threadIdx.x;

  if (blockIdx.x < 768) {                 // ---- W conversion ----
    const int idx = blockIdx.x * 256 + t;
    const int row = idx / PD_;
    float v = (row < 255) ? W_pe[idx] : 0.0f;
    const unsigned short h = f2bf(v);
    Whi[idx] = h;
    Wlo[idx] = f2bf(v - bf2f(h));
    return;
  }

  if (blockIdx.x < 800) {                 // ---- q projections ----
    const int b = blockIdx.x - 768;
    {
      const float4* emb = (const float4*)(image_embs + (size_t)b * DIMG_);
      const float4* wr  = (const float4*)(W_proj + (size_t)t * DIMG_);
      float a = b_proj[t];
      #pragma unroll 4
      for (int i = 0; i < DIMG_ / 4; ++i) {
        const float4 e4 = emb[i], w4 = wr[i];
        a += e4.x * w4.x + e4.y * w4.y + e4.z * w4.z + e4.w * w4.w;
      }
      q1[t] = a;
    }
    __syncthreads();
    {
      const float4* wr = (const float4*)(in_w + (size_t)t * DD);
      const float4* qq = (const float4*)q1;
      float a = in_b[t];
      #pragma unroll 4
      for (int i = 0; i < DD / 4; ++i) {
        const float4 q4 = qq[i], w4 = wr[i];
        a += q4.x * w4.x + q4.y * w4.y + q4.z * w4.z + q4.w * w4.w;
      }
      q2[t] = a;
    }
    __syncthreads();
    #pragma unroll
    for (int h = 0; h < NHEADS; ++h) {
      float s = 0.0f;
      #pragma unroll 8
      for (int i = 0; i < 32; ++i)
        s += q2[h * 32 + i] * in_w[(size_t)(DD + h * 32 + i) * DD + t];
      u_out[((size_t)b * NHEADS + h) * DD + t] = s;
    }
    if (t < NHEADS) {
      float s = 0.0f;
      for (int i = 0; i < 32; ++i) s += q2[t * 32 + i] * in_b[DD + t * 32 + i];
      bias_out[b * NHEADS + t] = s;
    }
    return;
  }

  // ---- patch extract + LN1 (one wave per patch) ----
  const int L  = t & 63;
  const long gp = (long)(blockIdx.x - 800) * 4 + (t >> 6);
  const int b   = (int)(gp >> 10);
  const int n2  = (int)(gp & 1023);
  const bool side1 = (n2 >= NN);
  const float* img  = side1 ? im1 : im0;
  const float* kpts = side1 ? kpts1 : kpts0;
  const float* scrs = side1 ? scores1 : scores0;

  const int n  = side1 ? (n2 - NN) : n2;
  const int m0 = sorted_matches[((size_t)b * NN + n) * 2 + 0];
  const int m1 = sorted_matches[((size_t)b * NN + n) * 2 + 1];
  const bool valid = (m1 > -1);
  int midx = side1 ? m1 : m0;
  midx = min(max(midx, 0), MM - 1);
  const float kx = kpts[((size_t)b * MM + midx) * 2 + 0];
  const float ky = kpts[((size_t)b * MM + midx) * 2 + 1];
  const int x0 = min(max((int)rintf(kx) - 8, 0), WW - PSZ);
  const int y0 = min(max((int)rintf(ky) - 8, 0), HH - PSZ);

  float v[12];
  if (valid) {
    const size_t imb = (size_t)b * 3 * HH * WW;
    const int px = (2 * L) & 15;
    #pragma unroll
    for (int j = 0; j < 6; ++j) {
      const int p0 = 2 * L + 128 * j;
      const int c  = p0 >> 8;
      const int py = (p0 >> 4) & 15;
      const float* rp = img + imb + ((size_t)c * HH + y0 + py) * WW + x0 + px;
      v[2 * j]     = fminf(fmaxf(rp[0], 0.0f), 1.0f);
      v[2 * j + 1] = fminf(fmaxf(rp[1], 0.0f), 1.0f);
    }
  } else {
    #pragma unroll
    for (int i = 0; i < 12; ++i) v[i] = -1.0f;
  }

  float s = 0.0f, ss = 0.0f;
  #pragma unroll
  for (int i = 0; i < 12; ++i) { s += v[i]; ss += v[i] * v[i]; }
  #pragma unroll
  for (int m = 32; m; m >>= 1) { s += __shfl_xor(s, m); ss += __shfl_xor(ss, m); }
  const float mu  = s * (1.0f / 768.0f);
  const float var = ss * (1.0f / 768.0f) - mu * mu;
  const float rs  = 1.0f / sqrtf(var + 1e-5f);

  unsigned int* AhiW = (unsigned int*)(Ahi + gp * PD_);
  unsigned int* AloW = (unsigned int*)(Alo + gp * PD_);
  #pragma unroll
  for (int j = 0; j < 6; ++j) {
    const int p0 = 2 * L + 128 * j;
    const float y0e = (v[2 * j]     - mu) * rs * ln1_g[p0]     + ln1_b[p0];
    const float y1e = (v[2 * j + 1] - mu) * rs * ln1_g[p0 + 1] + ln1_b[p0 + 1];
    const unsigned short h0 = f2bf(y0e), h1 = f2bf(y1e);
    AhiW[p0 >> 1] = (unsigned int)h0 | ((unsigned int)h1 << 16);
    const unsigned short l0 = f2bf(y0e - bf2f(h0));
    const unsigned short l1 = f2bf(y1e - bf2f(h1));
    AloW[p0 >> 1] = (unsigned int)l0 | ((unsigned int)l1 << 16);
  }
  if (L == 0) {
    score_all[gp] = valid ? scrs[(size_t)b * MM + midx] : 0.0f;
  }
}

// ---------------------------------------------------------------------------
// Kernel 2: fused GEMM + LN2 + score-append -> pe.
// Tile: 64 rows x 256 cols, BK=32, 4 waves, 40 KB LDS,
// 512 blocks = 2 independent blocks/CU (cross-block overlap hides the
// per-K-step vmcnt drain; m97 2-barrier schedule).
// Epilogue: LN2 stats via 2.5 KB LDS cross-wave reduce (aliased onto
// staging LDS), write pe rows with score at col 255.
// ---------------------------------------------------------------------------
__global__ __launch_bounds__(256, 2) void gemm_fused_kernel(
    const unsigned short* __restrict__ Ahi, const unsigned short* __restrict__ Alo,
    const unsigned short* __restrict__ Whi, const unsigned short* __restrict__ Wlo,
    const float* __restrict__ b_pe,
    const float* __restrict__ ln2_g, const float* __restrict__ ln2_b,
    const float* __restrict__ score_all,
    float* __restrict__ pe)
{
  // shorts: AHI [64][32] @0, ALO @2048, BHI [256][32] @4096, BLO @12288
  __shared__ __align__(16) unsigned short sm[20480];   // 40960 B
  const int t = threadIdx.x;
  const int w = t >> 6, L = t & 63;
  const int mt = blockIdx.x;                 // 512 blocks, 64 rows each

  const int rr   = L >> 2;                   // row within 16-row chunk
  const int q_st = (L & 3) ^ ((L >> 4) & 3); // XOR-swizzled k-quad (store)
  const int lane_m = L & 15, quad = L >> 4;
  const int swz = quad ^ (lane_m >> 2);      // same swizzle on read

  // ---- staging chunk map: 40 x 1KB chunks; wave w owns cc = w + 4c ----
  const unsigned short* gsrc[10];
  int ldst[10];
  #pragma unroll
  for (int c = 0; c < 10; ++c) {
    const int cc = w + 4 * c;
    const unsigned short* sp; long rb; int dst;
    if (cc < 4)       { sp = Ahi; rb = (long)mt * 64 + cc * 16;       dst = cc * 512; }
    else if (cc < 8)  { sp = Alo; rb = (long)mt * 64 + (cc - 4) * 16; dst = 2048 + (cc - 4) * 512; }
    else if (cc < 24) { sp = Whi; rb = (long)(cc - 8) * 16;           dst = 4096 + (cc - 8) * 512; }
    else              { sp = Wlo; rb = (long)(cc - 24) * 16;          dst = 12288 + (cc - 24) * 512; }
    gsrc[c] = sp + (rb + rr) * (long)PD_ + q_st * 8;
    ldst[c] = dst;
  }

  f32x4 acc[4][4];
  #pragma unroll
  for (int i = 0; i < 4; ++i)
    #pragma unroll
    for (int j = 0; j < 4; ++j) acc[i][j] = (f32x4){0.f, 0.f, 0.f, 0.f};

  for (int ks = 0; ks < PD_ / 32; ++ks) {
    const int k0 = ks * 32;
    __syncthreads();                          // LDS free to overwrite
    #pragma unroll
    for (int c = 0; c < 10; ++c)
      gload_lds16(gsrc[c] + k0, sm + ldst[c]);
    __syncthreads();                          // staging complete (vmcnt drain)

    bf16x8 ah[4], al[4];
    #pragma unroll
    for (int i = 0; i < 4; ++i) {
      const int offa = (i * 16 + lane_m) * 32 + swz * 8;
      ah[i] = *(const bf16x8*)(sm + offa);
      al[i] = *(const bf16x8*)(sm + 2048 + offa);
    }
    #pragma unroll
    for (int j = 0; j < 4; ++j) {
      const int offb = (w * 64 + j * 16 + lane_m) * 32 + swz * 8;
      const bf16x8 bh = *(const bf16x8*)(sm + 4096 + offb);
      const bf16x8 bl = *(const bf16x8*)(sm + 12288 + offb);
      #pragma unroll
      for (int i = 0; i < 4; ++i) {
        acc[i][j] = __builtin_amdgcn_mfma_f32_16x16x32_bf16(ah[i], bh, acc[i][j], 0, 0, 0);
        acc[i][j] = __builtin_amdgcn_mfma_f32_16x16x32_bf16(ah[i], bl, acc[i][j], 0, 0, 0);
        acc[i][j] = __builtin_amdgcn_mfma_f32_16x16x32_bf16(al[i], bh, acc[i][j], 0, 0, 0);
      }
    }
  }

  // ---- fused epilogue: LN2 + score append ----
  __syncthreads();                            // staging reads done; alias LDS
  float* const fs = (float*)sm;               // [0,256) s  [256,512) ss
                                              // [512,576) mu [576,640) rs
  float p4[4], g4[4], b4[4];
  #pragma unroll
  for (int j = 0; j < 4; ++j) {
    const int c = w * 64 + j * 16 + lane_m;
    const bool cv = (c < 255);
    p4[j] = cv ? b_pe[c]  : 0.0f;
    g4[j] = cv ? ln2_g[c] : 0.0f;
    b4[j] = cv ? ln2_b[c] : 0.0f;
  }
  // stats: col 255 contributes exactly 0 (e==0 from zero W row, p4==0)
  float sv[16], qv[16];
  #pragma unroll
  for (int i = 0; i < 4; ++i)
    #pragma unroll
    for (int v = 0; v < 4; ++v) {
      float s = 0.0f, q = 0.0f;
      #pragma unroll
      for (int j = 0; j < 4; ++j) {
        const float x = acc[i][j][v] + p4[j];
        s += x; q += x * x;
      }
      sv[i * 4 + v] = s; qv[i * 4 + v] = q;
    }
  #pragma unroll
  for (int iv = 0; iv < 16; ++iv) {
    #pragma unroll
    for (int m = 1; m <= 8; m <<= 1) {
      sv[iv] += __shfl_xor(sv[iv], m);
      qv[iv] += __shfl_xor(qv[iv], m);
    }
  }
  if (lane_m == 0) {
    #pragma unroll
    for (int i = 0; i < 4; ++i)
      #pragma unroll
      for (int v = 0; v < 4; ++v) {
        const int row = i * 16 + quad * 4 + v;
        fs[w * 64 + row]       = sv[i * 4 + v];
        fs[256 + w * 64 + row] = qv[i * 4 + v];
      }
  }
  __syncthreads();
  if (t < 64) {
    const float S  = fs[t] + fs[64 + t] + fs[128 + t] + fs[192 + t];
    const float SS = fs[256 + t] + fs[320 + t] + fs[384 + t] + fs[448 + t];
    const float mu  = S * (1.0f / 255.0f);
    const float var = SS * (1.0f / 255.0f) - mu * mu;
    fs[512 + t] = mu;
    fs[576 + t] = 1.0f / sqrtf(var + 1e-5f);
  }
  __syncthreads();

  #pragma unroll
  for (int i = 0; i < 4; ++i)
    #pragma unroll
    for (int v = 0; v < 4; ++v) {
      const int row = i * 16 + quad * 4 + v;
      const long grow = (long)mt * 64 + row;
      const float mu = fs[512 + row];
      const float rs = fs[576 + row];
      float sc = 0.0f;
      if (w == 3) sc = score_all[grow];
      float* rowp = pe + grow * DD + w * 64 + lane_m;
      #pragma unroll
      for (int j = 0; j < 4; ++j) {
        const int c = w * 64 + j * 16 + lane_m;
        const float y = (c < 255)
            ? (acc[i][j][v] + p4[j] - mu) * rs * g4[j] + b4[j]
            : sc;
        rowp[j * 16] = y;
      }
    }
}

// ---------------------------------------------------------------------------
// Kernel 3: logits lt[row][h] = (pe_row . u[b,h] + ubias[b,h]) / sqrt(32).
// 4096 blocks, 8 rows/block, 32 lanes/row; pe is L2/L3-resident.
// ---------------------------------------------------------------------------
__global__ __launch_bounds__(256) void logits_kernel(
    const float* __restrict__ pe,
    const float* __restrict__ u, const float* __restrict__ ubias,
    float* __restrict__ lt)
{
  __shared__ __align__(16) float u_sh[NHEADS * DD];   // 8 KB
  __shared__ float ub_sh[NHEADS];
  const int t = threadIdx.x;
  const long row0 = (long)blockIdx.x * 8;
  const int b = (int)(row0 >> 10);                    // 128 blocks per batch

  const float* ub = u + (size_t)b * NHEADS * DD;
  #pragma unroll
  for (int i = 0; i < 8; ++i) u_sh[t + 256 * i] = ub[t + 256 * i];
  if (t < NHEADS) ub_sh[t] = ubias[b * NHEADS + t];
  __syncthreads();

  const int r = t >> 5, l = t & 31;
  const long row = row0 + r;
  const float4* pr4 = (const float4*)(pe + row * DD);
  float d[NHEADS] = {0, 0, 0, 0, 0, 0, 0, 0};
  #pragma unroll
  for (int half = 0; half < 2; ++half) {
    const float4 x = pr4[l + 32 * half];
    #pragma unroll
    for (int h = 0; h < NHEADS; ++h) {
      const float4 uu = *(const float4*)&u_sh[h * DD + 4 * (l + 32 * half)];
      d[h] += x.x * uu.x + x.y * uu.y + x.z * uu.z + x.w * uu.w;
    }
  }
  #pragma unroll
  for (int h = 0; h < NHEADS; ++h) {
    #pragma unroll
    for (int m = 16; m; m >>= 1) d[h] += __shfl_xor(d[h], m, 32);
  }
  if (l == 0) {
    #pragma unroll
    for (int h = 0; h < NHEADS; ++h)
      lt[row * NHEADS + h] = (d[h] + ub_sh[h]) * 0.17677669529663687f; // 1/sqrt(32)
  }
}

// ---------------------------------------------------------------------------
// Kernel 4: softmax over 1024 keys per batch -> prg[b][k][h] (1 MB, L2)
// ---------------------------------------------------------------------------
__global__ __launch_bounds__(256) void softmax_kernel(
    const float* __restrict__ lt, float* __restrict__ prg)
{
  const int b = blockIdx.x, t = threadIdx.x;
  const int h = t >> 5, l = t & 31;
  const float* base = lt + (size_t)b * TWO_N * NHEADS + h;
  float v[32];
  float mx = -1e30f;
  #pragma unroll 8
  for (int i = 0; i < 32; ++i) { v[i] = base[(l + 32 * i) * NHEADS]; mx = fmaxf(mx, v[i]); }
  #pragma unroll
  for (int m = 16; m; m >>= 1) mx = fmaxf(mx, __shfl_xor(mx, m, 32));
  float sm = 0.0f;
  #pragma unroll 8
  for (int i = 0; i < 32; ++i) { v[i] = expf(v[i] - mx); sm += v[i]; }
  #pragma unroll
  for (int m = 16; m; m >>= 1) sm += __shfl_xor(sm, m, 32);
  const float inv = 1.0f / sm;
  float* out = prg + (size_t)b * TWO_N * NHEADS + h;
  #pragma unroll 8
  for (int i = 0; i < 32; ++i) out[(l + 32 * i) * NHEADS] = v[i] * inv;
}

// ---------------------------------------------------------------------------
// Kernel 5: partial ctx over 32-key chunks. 1024 blocks (4/CU), 1 KB LDS.
// ---------------------------------------------------------------------------
__global__ __launch_bounds__(256) void ctx_kernel(
    const float* __restrict__ pe, const float* __restrict__ prg,
    float* __restrict__ ctxp)
{
  __shared__ __align__(16) float prc[32 * NHEADS];   // 1 KB
  const int b = blockIdx.x, ch = blockIdx.y, t = threadIdx.x;
  prc[t] = prg[((size_t)b * TWO_N + ch * 32) * NHEADS + t];
  __syncthreads();

  const float* peb = pe + ((size_t)b * TWO_N + ch * 32) * DD;
  float acc[NHEADS] = {0, 0, 0, 0, 0, 0, 0, 0};
  #pragma unroll 4
  for (int k = 0; k < 32; ++k) {
    const float v = peb[(size_t)k * DD + t];           // coalesced
    const float4 a0 = *(const float4*)&prc[k * NHEADS];
    const float4 a1 = *(const float4*)&prc[k * NHEADS + 4];
    acc[0] += a0.x * v; acc[1] += a0.y * v; acc[2] += a0.z * v; acc[3] += a0.w * v;
    acc[4] += a1.x * v; acc[5] += a1.y * v; acc[6] += a1.z * v; acc[7] += a1.w * v;
  }
  #pragma unroll
  for (int h = 0; h < NHEADS; ++h)
    ctxp[(((size_t)b * CHCT + ch) * NHEADS + h) * DD + t] = acc[h];
}

// ---------------------------------------------------------------------------
// Kernel 6: reduce ctx partials + Wv + out_w + W_fc head
// ---------------------------------------------------------------------------
__global__ __launch_bounds__(256) void final_kernel(
    const float* __restrict__ ctxp,
    const float* __restrict__ in_w,  const float* __restrict__ in_b,
    const float* __restrict__ out_w, const float* __restrict__ out_b,
    const float* __restrict__ W_fc,  const float* __restrict__ b_fc,
    float* __restrict__ outp)
{
  __shared__ __align__(16) float ctx_sh[NHEADS * DD];
  __shared__ __align__(16) float o_sh[DD], o2_sh[DD];
  const int t = threadIdx.x;
  const int b = blockIdx.x;

  #pragma unroll
  for (int h = 0; h < NHEADS; ++h) {
    float s = 0.0f;
    #pragma unroll
    for (int ch = 0; ch < CHCT; ++ch)
      s += ctxp[(((size_t)b * CHCT + ch) * NHEADS + h) * DD + t];
    ctx_sh[h * DD + t] = s;
  }
  __syncthreads();
  {
    const float4* wv = (const float4*)(in_w + (size_t)(2 * DD + t) * DD);
    const float4* cx = (const float4*)(ctx_sh + (t >> 5) * DD);
    float o1 = in_b[2 * DD + t];
    #pragma unroll 4
    for (int j = 0; j < DD / 4; ++j) {
      const float4 w4 = wv[j], c4 = cx[j];
      o1 += w4.x * c4.x + w4.y * c4.y + w4.z * c4.z + w4.w * c4.w;
    }
    o_sh[t] = o1;
  }
  __syncthreads();
  {
    const float4* wr = (const float4*)(out_w + (size_t)t * DD);
    const float4* oo = (const float4*)o_sh;
    float o2 = out_b[t];
    #pragma unroll 4
    for (int j = 0; j < DD / 4; ++j) {
      const float4 w4 = wr[j], c4 = oo[j];
      o2 += w4.x * c4.x + w4.y * c4.y + w4.z * c4.z + w4.w * c4.w;
    }
    o2_sh[t] = o2;
  }
  __syncthreads();
  if (t < 6) {
    const float4* wr = (const float4*)(W_fc + (size_t)t * DD);
    const float4* oo = (const float4*)o2_sh;
    float r = b_fc[t];
    for (int j = 0; j < DD / 4; ++j) {
      const float4 w4 = wr[j], c4 = oo[j];
      r += w4.x * c4.x + w4.y * c4.y + w4.z * c4.z + w4.w * c4.w;
    }
    outp[b * 6 + t] = r;
  }
}

// ---------------------------------------------------------------------------
extern "C" void kernel_launch(void* const* d_in, const int* in_sizes, int n_in,
                              void* d_out, int out_size, void* d_ws, size_t ws_size,
                              hipStream_t stream) {
  const float* im0       = (const float*)d_in[0];
  const float* im1       = (const float*)d_in[1];
  const float* kpts0     = (const float*)d_in[2];
  const float* kpts1     = (const float*)d_in[3];
  const float* scores0   = (const float*)d_in[4];
  const float* scores1   = (const float*)d_in[5];
  const float* image_embs= (const float*)d_in[6];
  const int*   smatch    = (const int*)d_in[7];
  const float* ln1_g     = (const float*)d_in[8];
  const float* ln1_b     = (const float*)d_in[9];
  const float* W_pe      = (const float*)d_in[10];
  const float* b_pe      = (const float*)d_in[11];
  const float* ln2_g     = (const float*)d_in[12];
  const float* ln2_b     = (const float*)d_in[13];
  const float* W_proj    = (const float*)d_in[14];
  const float* b_proj    = (const float*)d_in[15];
  const float* in_w      = (const float*)d_in[16];
  const float* in_b      = (const float*)d_in[17];
  const float* out_w     = (const float*)d_in[18];
  const float* out_b     = (const float*)d_in[19];
  const float* W_fc      = (const float*)d_in[20];
  const float* b_fc      = (const float*)d_in[21];

  // ---- workspace layout (bytes) ----
  char* ws = (char*)d_ws;
  size_t off = 0;
  float* epe   = (float*)(ws + off); off += (size_t)ROWS_TOT * DD * 4;        // 32 MB (pe)
  float* u     = (float*)(ws + off); off += (size_t)BB * NHEADS * DD * 4;     // 256 KB
  float* ubias = (float*)(ws + off); off += (size_t)BB * NHEADS * 4;
  off = (off + 1023) & ~(size_t)1023;
  float* score = (float*)(ws + off); off += (size_t)ROWS_TOT * 4;             // 128 KB
  float* lt    = (float*)(ws + off); off += (size_t)BB * TWO_N * NHEADS * 4;  // 1 MB
  float* prg   = (float*)(ws + off); off += (size_t)BB * TWO_N * NHEADS * 4;  // 1 MB
  float* ctxp  = (float*)(ws + off); off += (size_t)BB * CHCT * NHEADS * DD * 4; // 8 MB
  off = (off + 1023) & ~(size_t)1023;
  unsigned short* Whi = (unsigned short*)(ws + off); off += (size_t)256 * PD_ * 2;
  unsigned short* Wlo = (unsigned short*)(ws + off); off += (size_t)256 * PD_ * 2;
  off = (off + 1023) & ~(size_t)1023;
  unsigned short* Ahi = (unsigned short*)(ws + off); off += (size_t)ROWS_TOT * PD_ * 2; // 50 MB
  unsigned short* Alo = (unsigned short*)(ws + off); off += (size_t)ROWS_TOT * PD_ * 2; // 50 MB

  prep_extract_kernel<<<800 + ROWS_TOT / 4, 256, 0, stream>>>(
      W_pe, Whi, Wlo, image_embs, W_proj, b_proj, in_w, in_b, u, ubias,
      im0, im1, kpts0, kpts1, scores0, scores1, smatch,
      ln1_g, ln1_b, Ahi, Alo, score);
  gemm_fused_kernel<<<ROWS_TOT / 64, 256, 0, stream>>>(
      Ahi, Alo, Whi, Wlo, b_pe, ln2_g, ln2_b, score, epe);
  logits_kernel<<<ROWS_TOT / 8, 256, 0, stream>>>(epe, u, ubias, lt);
  softmax_kernel<<<BB, 256, 0, stream>>>(lt, prg);
  ctx_kernel<<<dim3(BB, CHCT), 256, 0, stream>>>(epe, prg, ctxp);
  final_kernel<<<BB, 256, 0, stream>>>(ctxp, in_w, in_b, out_w, out_b,
                                       W_fc, b_fc, (float*)d_out);
}